// Round 34
// baseline (71.648 us; speedup 1.0000x reference)
//
#include <hip/hip_runtime.h>

// MMoE: B=16384 D=512 U=128 E=16 T=4, fp32 in/out.
// FINAL ARTIFACT = ROUND-30/32 VERBATIM (proven: passed r30+r32 at
// 70.6-70.7us). r33's setprio removal caused a replay race — the setprio
// pair doubles as a compiler-scheduling fence around the MFMA cluster
// (rule-#18-class hazard); it is REQUIRED, not just a perf hint.
// Pipeline: prep (8-wave MFMA hi/lo gates ~= f32 logits, fused x->xb bf16
// emission, coalesced gk staging; + ek->ekT bf16 transpose) then moe
// (128x256 tile, 8 waves, BK=32, triple-buffered 72KB LDS, counted
// vmcnt(3)+s_barrier depth-2 pipeline, gload_lds with src/read swizzle
// pair, XCD swizzle, setprio-fenced MFMA cluster, fused bias+relu+gate
// contraction epilogue with float4 gate reads via [b][e*4+t] layout).
// ws: gates 4MiB @0, xb 16MiB @4, ekT 2MiB @20.

#define Bsz 16384
#define Dd  512
#define Uu  128
#define Ee  16
#define Tt  4
#define Nn  2048   // U*E

typedef short bf16x8 __attribute__((ext_vector_type(8)));
typedef float f32x4 __attribute__((ext_vector_type(4)));
typedef unsigned short u16x8 __attribute__((ext_vector_type(8)));

static __device__ __forceinline__ unsigned short f2bf(float f) {
    unsigned int u = __builtin_bit_cast(unsigned int, f);
    u += 0x7fffu + ((u >> 16) & 1u);   // round-to-nearest-even
    return (unsigned short)(u >> 16);
}
static __device__ __forceinline__ float bf2f(unsigned short s) {
    return __builtin_bit_cast(float, (unsigned int)s << 16);
}

#define GLOAD16(g, l) __builtin_amdgcn_global_load_lds( \
    (const __attribute__((address_space(1))) void*)(g), \
    (__attribute__((address_space(3))) void*)(l), 16, 0, 0)

// ---------------- Kernel A: prep = MFMA-gates (+x->xb) U convert_ek ----------------
// 512 threads. blocks [0,256): gates, 64 rows, 8 waves (2 ni/wave).
// blocks [256,512): ek [512][2048] -> ekT [2048][512] bf16.
#define GLD 72  // padded LDS row stride (shorts); 144B, 16B-aligned
__global__ __launch_bounds__(512) void prep_kernel(
        const float* __restrict__ x, const float* __restrict__ gk,
        const float* __restrict__ gb, const float* __restrict__ ek,
        float* __restrict__ gates, unsigned short* __restrict__ xb,
        unsigned short* __restrict__ ekT) {
    __shared__ __align__(16) unsigned short pm[4 * 64 * GLD];  // 36864 B
    const int tid = threadIdx.x;
    if (blockIdx.x >= 256) {
        unsigned short* ts = pm;  // [64*65]
        const int b2 = blockIdx.x - 256;
        const int n0 = (b2 & 31) * 64, d0 = (b2 >> 5) * 64;
        #pragma unroll
        for (int i = 0; i < 2; ++i) {
            int flat = i * 512 + tid;
            int dl = flat >> 4, ng = (flat & 15) * 4;
            const float4 v = *(const float4*)(ek + (size_t)(d0 + dl) * Nn + n0 + ng);
            ts[(ng + 0) * 65 + dl] = f2bf(v.x);
            ts[(ng + 1) * 65 + dl] = f2bf(v.y);
            ts[(ng + 2) * 65 + dl] = f2bf(v.z);
            ts[(ng + 3) * 65 + dl] = f2bf(v.w);
        }
        __syncthreads();
        #pragma unroll
        for (int i = 0; i < 2; ++i) {
            int flat = i * 512 + tid;
            int nl = flat >> 4, dg = (flat & 15) * 4;
            ushort4 w = make_ushort4(ts[nl * 65 + dg], ts[nl * 65 + dg + 1],
                                     ts[nl * 65 + dg + 2], ts[nl * 65 + dg + 3]);
            *(ushort4*)(ekT + (size_t)(n0 + nl) * Dd + d0 + dg) = w;
        }
        return;
    }
    // ---- gates: 64 rows, 8 waves; wave w -> rows (w&3)*16..+15, ni-half w>>2 ----
    unsigned short* sAh = pm;                 // [64][GLD]
    unsigned short* sAl = pm + 64 * GLD;
    unsigned short* sBh = pm + 2 * 64 * GLD;  // [n][GLD] (n = t*16+e)
    unsigned short* sBl = pm + 3 * 64 * GLD;
    const int w = tid >> 6, lane = tid & 63;
    const int llo = lane & 15, lhi = lane >> 4;
    const int wg = w & 3, wq = w >> 2;
    const int b0 = blockIdx.x * 64;
    f32x4 acc[2] = {};

    for (int c = 0; c < 8; ++c) {
        const int d0 = c * 64;
        __syncthreads();  // previous chunk consumed
        // stage x 64rows x 64d: split hi/lo; hi ushort4 also -> xb (== f2bf(x))
        #pragma unroll
        for (int p = 0; p < 2; ++p) {
            const int flat = p * 512 + tid;
            const int row = flat >> 4, c4 = (flat & 15) * 4;
            const float4 v = *(const float4*)(x + (size_t)(b0 + row) * Dd + d0 + c4);
            unsigned short h0 = f2bf(v.x), h1 = f2bf(v.y), h2 = f2bf(v.z), h3 = f2bf(v.w);
            const ushort4 hv = make_ushort4(h0, h1, h2, h3);
            *(ushort4*)(sAh + row * GLD + c4) = hv;
            *(ushort4*)(sAl + row * GLD + c4) = make_ushort4(
                f2bf(v.x - bf2f(h0)), f2bf(v.y - bf2f(h1)),
                f2bf(v.z - bf2f(h2)), f2bf(v.w - bf2f(h3)));
            *(ushort4*)(xb + (size_t)(b0 + row) * Dd + d0 + c4) = hv;
        }
        // stage gk chunk coalesced: f -> t=f>>8, dl=(f>>2)&63, e4=f&3
        #pragma unroll
        for (int p = 0; p < 2; ++p) {
            const int f = p * 512 + tid;
            const int t_ = f >> 8, dl = (f >> 2) & 63, e4 = f & 3;
            const float4 v = *(const float4*)(gk + (size_t)t_ * (Dd * Ee)
                                              + (size_t)(d0 + dl) * Ee + e4 * 4);
            const int nb = t_ * 16 + e4 * 4;
            unsigned short h0 = f2bf(v.x), h1 = f2bf(v.y), h2 = f2bf(v.z), h3 = f2bf(v.w);
            sBh[(nb + 0) * GLD + dl] = h0;
            sBh[(nb + 1) * GLD + dl] = h1;
            sBh[(nb + 2) * GLD + dl] = h2;
            sBh[(nb + 3) * GLD + dl] = h3;
            sBl[(nb + 0) * GLD + dl] = f2bf(v.x - bf2f(h0));
            sBl[(nb + 1) * GLD + dl] = f2bf(v.y - bf2f(h1));
            sBl[(nb + 2) * GLD + dl] = f2bf(v.z - bf2f(h2));
            sBl[(nb + 3) * GLD + dl] = f2bf(v.w - bf2f(h3));
        }
        __syncthreads();
        #pragma unroll
        for (int ks = 0; ks < 64; ks += 32) {
            const bf16x8 ah = *(const bf16x8*)(sAh + (wg * 16 + llo) * GLD + ks + lhi * 8);
            const bf16x8 al = *(const bf16x8*)(sAl + (wg * 16 + llo) * GLD + ks + lhi * 8);
            #pragma unroll
            for (int q = 0; q < 2; ++q) {
                const int nio = wq * 2 + q;
                const bf16x8 bh = *(const bf16x8*)(sBh + (nio * 16 + llo) * GLD + ks + lhi * 8);
                const bf16x8 bl = *(const bf16x8*)(sBl + (nio * 16 + llo) * GLD + ks + lhi * 8);
                acc[q] = __builtin_amdgcn_mfma_f32_16x16x32_bf16(ah, bh, acc[q], 0, 0, 0);
                acc[q] = __builtin_amdgcn_mfma_f32_16x16x32_bf16(al, bh, acc[q], 0, 0, 0);
                acc[q] = __builtin_amdgcn_mfma_f32_16x16x32_bf16(ah, bl, acc[q], 0, 0, 0);
            }
        }
    }
    // softmax over e (= llo lanes) per task t (= nio); store gates[b][e*4+t]
    #pragma unroll
    for (int q = 0; q < 2; ++q) {
        const int nio = wq * 2 + q;
        const float bias = gb[nio * 16 + llo];
        #pragma unroll
        for (int j = 0; j < 4; ++j) {
            float lg = acc[q][j] + bias;
            float m = lg;
            m = fmaxf(m, __shfl_xor(m, 1));
            m = fmaxf(m, __shfl_xor(m, 2));
            m = fmaxf(m, __shfl_xor(m, 4));
            m = fmaxf(m, __shfl_xor(m, 8));
            float p = __expf(lg - m);
            float s = p;
            s += __shfl_xor(s, 1);
            s += __shfl_xor(s, 2);
            s += __shfl_xor(s, 4);
            s += __shfl_xor(s, 8);
            const int row = b0 + wg * 16 + lhi * 4 + j;  // C frag: row=(lane>>4)*4+j
            gates[(size_t)row * 64 + llo * 4 + nio] = p / s;  // [b][e*4+t]
        }
    }
}

// ---------------- Kernel B: expert GEMM + relu + gate contraction ----------------
// r22/r30 VERBATIM: 128x256, 8 waves, BK=32, triple-buffer 72KB, vmcnt(3).
#define BM 128
#define BN 256
#define BK 32

#define ST_A(buf, kt_) {                                                        \
    const int c_ = wave * 64 + lane;                                            \
    const int r_ = c_ >> 2;                                                     \
    const int l_ = (c_ & 3) ^ ((r_ >> 2) & 3);                                  \
    GLOAD16(xb + (size_t)(b0 + r_) * Dd + (kt_) * BK + l_ * 8,                  \
            smem + (buf) * 24576 + c_ * 16); }
#define ST_B(buf, kt_) { _Pragma("unroll")                                      \
    for (int i_ = 0; i_ < 2; ++i_) {                                            \
        const int c_ = i_ * 512 + wave * 64 + lane;                             \
        const int r_ = c_ >> 2;                                                 \
        const int l_ = (c_ & 3) ^ ((r_ >> 2) & 3);                              \
        GLOAD16(ekT + (size_t)(n0 + r_) * Dd + (kt_) * BK + l_ * 8,             \
                smem + (buf) * 24576 + 8192 + c_ * 16); } }
#define STAGE(buf, kt_) { ST_A(buf, kt_) ST_B(buf, kt_) }  // 3 loads/wave

__global__ __launch_bounds__(512) void moe_kernel(
        const unsigned short* __restrict__ xb,
        const unsigned short* __restrict__ ekT,
        const float* __restrict__ eb, const float* __restrict__ gates,
        float* __restrict__ out) {
    __shared__ __align__(64) char smem[73728];  // 3 bufs x (A 8K + B 16K)
    const int tid = threadIdx.x;
    const int wave = tid >> 6, lane = tid & 63;
    const int llo = lane & 15, lhi = lane >> 4;
    const int g = (blockIdx.x & 7) * 128 + (blockIdx.x >> 3);  // XCD swizzle
    const int b0 = (g >> 3) * BM;
    const int n0 = (g & 7) * BN;
    const int mr = (wave >> 2) * 64, nc = (wave & 3) * 64;
    f32x4 acc[4][4] = {};

    STAGE(0, 0);
    STAGE(1, 1);
    for (int kt = 0; kt < Dd / BK; ++kt) {
        const char* aB = smem + (kt % 3) * 24576;
        const char* bB = aB + 8192;
        if (kt < 15) asm volatile("s_waitcnt vmcnt(3)\ns_barrier" ::: "memory");
        else         asm volatile("s_waitcnt vmcnt(0)\ns_barrier" ::: "memory");
        if (kt < 14) STAGE((kt + 2) % 3, kt + 2);  // buf last read in kt-1
        {
            const int ph = (lhi ^ (llo >> 2)) << 4;
            bf16x8 aF[4], bF[4];
            #pragma unroll
            for (int mi = 0; mi < 4; ++mi)
                aF[mi] = *(const bf16x8*)(aB + (mr + mi * 16 + llo) * 64 + ph);
            #pragma unroll
            for (int ni = 0; ni < 4; ++ni)
                bF[ni] = *(const bf16x8*)(bB + (nc + ni * 16 + llo) * 64 + ph);
            __builtin_amdgcn_s_setprio(1);   // also a scheduling fence (r33 lesson)
            #pragma unroll
            for (int mi = 0; mi < 4; ++mi)
                #pragma unroll
                for (int ni = 0; ni < 4; ++ni)
                    acc[mi][ni] = __builtin_amdgcn_mfma_f32_16x16x32_bf16(
                        aF[mi], bF[ni], acc[mi][ni], 0, 0, 0);
            __builtin_amdgcn_s_setprio(0);
        }
    }
    __syncthreads();  // all reads done; safe to overlay eo on staging LDS

    unsigned short* eo = (unsigned short*)smem;
    #pragma unroll
    for (int ni = 0; ni < 4; ++ni) {
        const int col = nc + ni * 16 + llo;
        const float ebv = eb[n0 + col];
        #pragma unroll
        for (int mi = 0; mi < 4; ++mi) {
            #pragma unroll
            for (int j = 0; j < 4; ++j) {
                int row = mr + mi * 16 + lhi * 4 + j;
                eo[row * 264 + col] = f2bf(fmaxf(acc[mi][ni][j] + ebv, 0.f));
            }
        }
    }
    __syncthreads();
    // contraction: out[t,b,u] = sum_e eo[b,u,e] * gates[b][e*4+t] (float4/e)
    #pragma unroll
    for (int i = 0; i < 4; ++i) {
        int f = i * 512 + tid;
        int m = f >> 4, ul = f & 15;
        const unsigned short* er = eo + m * 264 + ul * 16;
        const float* gr = gates + (size_t)(b0 + m) * 64;
        float o0 = 0.f, o1 = 0.f, o2 = 0.f, o3 = 0.f;
        #pragma unroll
        for (int e = 0; e < 16; ++e) {
            const float v = bf2f(er[e]);
            const float4 gv = *(const float4*)(gr + e * 4);
            o0 = fmaf(v, gv.x, o0);
            o1 = fmaf(v, gv.y, o1);
            o2 = fmaf(v, gv.z, o2);
            o3 = fmaf(v, gv.w, o3);
        }
        size_t base = (size_t)(b0 + m) * Uu + (n0 >> 4) + ul;
        out[base] = o0;
        out[(size_t)Bsz * Uu + base] = o1;
        out[2 * (size_t)Bsz * Uu + base] = o2;
        out[3 * (size_t)Bsz * Uu + base] = o3;
    }
}

extern "C" void kernel_launch(void* const* d_in, const int* in_sizes, int n_in,
                              void* d_out, int out_size, void* d_ws, size_t ws_size,
                              hipStream_t stream) {
    const float* x  = (const float*)d_in[0];
    const float* ek = (const float*)d_in[1];
    const float* eb = (const float*)d_in[2];
    const float* gk = (const float*)d_in[3];
    const float* gb = (const float*)d_in[4];
    float* out = (float*)d_out;

    char* wsb = (char*)d_ws;
    float* gates       = (float*)wsb;                            // 4 MiB @ 0
    unsigned short* xb  = (unsigned short*)(wsb + (4u << 20));   // 16 MiB @ 4
    unsigned short* ekT = (unsigned short*)(wsb + (20u << 20));  // 2 MiB @ 20

    prep_kernel<<<512, 512, 0, stream>>>(x, gk, gb, ek, gates, xb, ekT);
    moe_kernel<<<(Bsz / BM) * (Nn / BN), 512, 0, stream>>>(xb, ekT, eb, gates, out);
}

// Round 35
// 70.539 us; speedup vs baseline: 1.0157x; 1.0157x over previous
//
#include <hip/hip_runtime.h>

// MMoE: B=16384 D=512 U=128 E=16 T=4, fp32 in/out.
// FINAL ARTIFACT (passed r30/r32/r34 at 70.6-71.6us, absmax 0.015625).
// Structural plateau of the counted-vmcnt pipeline family: moe LDS-read
// path (~27us incl. irreducible >=8-way b128 aliasing) exceeds the 13.8us
// MFMA floor; deeper schedules failed structurally (r20 race, r21 VGPR
// wall). setprio pair is REQUIRED (r33: removal -> replay race; acts as
// compiler scheduling fence).
// Pipeline: prep (8-wave MFMA hi/lo-split gates ~= f32 logits, fused
// x->xb bf16 emission, coalesced gk staging; + ek->ekT bf16 transpose)
// then moe (128x256 tile, 8 waves, BK=32, triple-buffered 72KB LDS,
// counted vmcnt(3)+s_barrier depth-2 pipeline, gload_lds with src/read
// swizzle pair, XCD swizzle, setprio-fenced MFMA cluster, fused
// bias+relu+gate-contraction epilogue, float4 gate reads [b][e*4+t]).
// ws: gates 4MiB @0, xb 16MiB @4, ekT 2MiB @20.

#define Bsz 16384
#define Dd  512
#define Uu  128
#define Ee  16
#define Tt  4
#define Nn  2048   // U*E

typedef short bf16x8 __attribute__((ext_vector_type(8)));
typedef float f32x4 __attribute__((ext_vector_type(4)));
typedef unsigned short u16x8 __attribute__((ext_vector_type(8)));

static __device__ __forceinline__ unsigned short f2bf(float f) {
    unsigned int u = __builtin_bit_cast(unsigned int, f);
    u += 0x7fffu + ((u >> 16) & 1u);   // round-to-nearest-even
    return (unsigned short)(u >> 16);
}
static __device__ __forceinline__ float bf2f(unsigned short s) {
    return __builtin_bit_cast(float, (unsigned int)s << 16);
}

#define GLOAD16(g, l) __builtin_amdgcn_global_load_lds( \
    (const __attribute__((address_space(1))) void*)(g), \
    (__attribute__((address_space(3))) void*)(l), 16, 0, 0)

// ---------------- Kernel A: prep = MFMA-gates (+x->xb) U convert_ek ----------------
// 512 threads. blocks [0,256): gates, 64 rows, 8 waves (2 ni/wave).
// blocks [256,512): ek [512][2048] -> ekT [2048][512] bf16.
#define GLD 72  // padded LDS row stride (shorts); 144B, 16B-aligned
__global__ __launch_bounds__(512) void prep_kernel(
        const float* __restrict__ x, const float* __restrict__ gk,
        const float* __restrict__ gb, const float* __restrict__ ek,
        float* __restrict__ gates, unsigned short* __restrict__ xb,
        unsigned short* __restrict__ ekT) {
    __shared__ __align__(16) unsigned short pm[4 * 64 * GLD];  // 36864 B
    const int tid = threadIdx.x;
    if (blockIdx.x >= 256) {
        unsigned short* ts = pm;  // [64*65]
        const int b2 = blockIdx.x - 256;
        const int n0 = (b2 & 31) * 64, d0 = (b2 >> 5) * 64;
        #pragma unroll
        for (int i = 0; i < 2; ++i) {
            int flat = i * 512 + tid;
            int dl = flat >> 4, ng = (flat & 15) * 4;
            const float4 v = *(const float4*)(ek + (size_t)(d0 + dl) * Nn + n0 + ng);
            ts[(ng + 0) * 65 + dl] = f2bf(v.x);
            ts[(ng + 1) * 65 + dl] = f2bf(v.y);
            ts[(ng + 2) * 65 + dl] = f2bf(v.z);
            ts[(ng + 3) * 65 + dl] = f2bf(v.w);
        }
        __syncthreads();
        #pragma unroll
        for (int i = 0; i < 2; ++i) {
            int flat = i * 512 + tid;
            int nl = flat >> 4, dg = (flat & 15) * 4;
            ushort4 w = make_ushort4(ts[nl * 65 + dg], ts[nl * 65 + dg + 1],
                                     ts[nl * 65 + dg + 2], ts[nl * 65 + dg + 3]);
            *(ushort4*)(ekT + (size_t)(n0 + nl) * Dd + d0 + dg) = w;
        }
        return;
    }
    // ---- gates: 64 rows, 8 waves; wave w -> rows (w&3)*16..+15, ni-half w>>2 ----
    unsigned short* sAh = pm;                 // [64][GLD]
    unsigned short* sAl = pm + 64 * GLD;
    unsigned short* sBh = pm + 2 * 64 * GLD;  // [n][GLD] (n = t*16+e)
    unsigned short* sBl = pm + 3 * 64 * GLD;
    const int w = tid >> 6, lane = tid & 63;
    const int llo = lane & 15, lhi = lane >> 4;
    const int wg = w & 3, wq = w >> 2;
    const int b0 = blockIdx.x * 64;
    f32x4 acc[2] = {};

    for (int c = 0; c < 8; ++c) {
        const int d0 = c * 64;
        __syncthreads();  // previous chunk consumed
        // stage x 64rows x 64d: split hi/lo; hi ushort4 also -> xb (== f2bf(x))
        #pragma unroll
        for (int p = 0; p < 2; ++p) {
            const int flat = p * 512 + tid;
            const int row = flat >> 4, c4 = (flat & 15) * 4;
            const float4 v = *(const float4*)(x + (size_t)(b0 + row) * Dd + d0 + c4);
            unsigned short h0 = f2bf(v.x), h1 = f2bf(v.y), h2 = f2bf(v.z), h3 = f2bf(v.w);
            const ushort4 hv = make_ushort4(h0, h1, h2, h3);
            *(ushort4*)(sAh + row * GLD + c4) = hv;
            *(ushort4*)(sAl + row * GLD + c4) = make_ushort4(
                f2bf(v.x - bf2f(h0)), f2bf(v.y - bf2f(h1)),
                f2bf(v.z - bf2f(h2)), f2bf(v.w - bf2f(h3)));
            *(ushort4*)(xb + (size_t)(b0 + row) * Dd + d0 + c4) = hv;
        }
        // stage gk chunk coalesced: f -> t=f>>8, dl=(f>>2)&63, e4=f&3
        #pragma unroll
        for (int p = 0; p < 2; ++p) {
            const int f = p * 512 + tid;
            const int t_ = f >> 8, dl = (f >> 2) & 63, e4 = f & 3;
            const float4 v = *(const float4*)(gk + (size_t)t_ * (Dd * Ee)
                                              + (size_t)(d0 + dl) * Ee + e4 * 4);
            const int nb = t_ * 16 + e4 * 4;
            unsigned short h0 = f2bf(v.x), h1 = f2bf(v.y), h2 = f2bf(v.z), h3 = f2bf(v.w);
            sBh[(nb + 0) * GLD + dl] = h0;
            sBh[(nb + 1) * GLD + dl] = h1;
            sBh[(nb + 2) * GLD + dl] = h2;
            sBh[(nb + 3) * GLD + dl] = h3;
            sBl[(nb + 0) * GLD + dl] = f2bf(v.x - bf2f(h0));
            sBl[(nb + 1) * GLD + dl] = f2bf(v.y - bf2f(h1));
            sBl[(nb + 2) * GLD + dl] = f2bf(v.z - bf2f(h2));
            sBl[(nb + 3) * GLD + dl] = f2bf(v.w - bf2f(h3));
        }
        __syncthreads();
        #pragma unroll
        for (int ks = 0; ks < 64; ks += 32) {
            const bf16x8 ah = *(const bf16x8*)(sAh + (wg * 16 + llo) * GLD + ks + lhi * 8);
            const bf16x8 al = *(const bf16x8*)(sAl + (wg * 16 + llo) * GLD + ks + lhi * 8);
            #pragma unroll
            for (int q = 0; q < 2; ++q) {
                const int nio = wq * 2 + q;
                const bf16x8 bh = *(const bf16x8*)(sBh + (nio * 16 + llo) * GLD + ks + lhi * 8);
                const bf16x8 bl = *(const bf16x8*)(sBl + (nio * 16 + llo) * GLD + ks + lhi * 8);
                acc[q] = __builtin_amdgcn_mfma_f32_16x16x32_bf16(ah, bh, acc[q], 0, 0, 0);
                acc[q] = __builtin_amdgcn_mfma_f32_16x16x32_bf16(al, bh, acc[q], 0, 0, 0);
                acc[q] = __builtin_amdgcn_mfma_f32_16x16x32_bf16(ah, bl, acc[q], 0, 0, 0);
            }
        }
    }
    // softmax over e (= llo lanes) per task t (= nio); store gates[b][e*4+t]
    #pragma unroll
    for (int q = 0; q < 2; ++q) {
        const int nio = wq * 2 + q;
        const float bias = gb[nio * 16 + llo];
        #pragma unroll
        for (int j = 0; j < 4; ++j) {
            float lg = acc[q][j] + bias;
            float m = lg;
            m = fmaxf(m, __shfl_xor(m, 1));
            m = fmaxf(m, __shfl_xor(m, 2));
            m = fmaxf(m, __shfl_xor(m, 4));
            m = fmaxf(m, __shfl_xor(m, 8));
            float p = __expf(lg - m);
            float s = p;
            s += __shfl_xor(s, 1);
            s += __shfl_xor(s, 2);
            s += __shfl_xor(s, 4);
            s += __shfl_xor(s, 8);
            const int row = b0 + wg * 16 + lhi * 4 + j;  // C frag: row=(lane>>4)*4+j
            gates[(size_t)row * 64 + llo * 4 + nio] = p / s;  // [b][e*4+t]
        }
    }
}

// ---------------- Kernel B: expert GEMM + relu + gate contraction ----------------
// 128x256, 8 waves, BK=32, triple-buffer 72KB, counted vmcnt(3), gload_lds.
#define BM 128
#define BN 256
#define BK 32

#define ST_A(buf, kt_) {                                                        \
    const int c_ = wave * 64 + lane;                                            \
    const int r_ = c_ >> 2;                                                     \
    const int l_ = (c_ & 3) ^ ((r_ >> 2) & 3);                                  \
    GLOAD16(xb + (size_t)(b0 + r_) * Dd + (kt_) * BK + l_ * 8,                  \
            smem + (buf) * 24576 + c_ * 16); }
#define ST_B(buf, kt_) { _Pragma("unroll")                                      \
    for (int i_ = 0; i_ < 2; ++i_) {                                            \
        const int c_ = i_ * 512 + wave * 64 + lane;                             \
        const int r_ = c_ >> 2;                                                 \
        const int l_ = (c_ & 3) ^ ((r_ >> 2) & 3);                              \
        GLOAD16(ekT + (size_t)(n0 + r_) * Dd + (kt_) * BK + l_ * 8,             \
                smem + (buf) * 24576 + 8192 + c_ * 16); } }
#define STAGE(buf, kt_) { ST_A(buf, kt_) ST_B(buf, kt_) }  // 3 loads/wave

__global__ __launch_bounds__(512) void moe_kernel(
        const unsigned short* __restrict__ xb,
        const unsigned short* __restrict__ ekT,
        const float* __restrict__ eb, const float* __restrict__ gates,
        float* __restrict__ out) {
    __shared__ __align__(64) char smem[73728];  // 3 bufs x (A 8K + B 16K)
    const int tid = threadIdx.x;
    const int wave = tid >> 6, lane = tid & 63;
    const int llo = lane & 15, lhi = lane >> 4;
    const int g = (blockIdx.x & 7) * 128 + (blockIdx.x >> 3);  // XCD swizzle
    const int b0 = (g >> 3) * BM;
    const int n0 = (g & 7) * BN;
    const int mr = (wave >> 2) * 64, nc = (wave & 3) * 64;
    f32x4 acc[4][4] = {};

    STAGE(0, 0);
    STAGE(1, 1);
    for (int kt = 0; kt < Dd / BK; ++kt) {
        const char* aB = smem + (kt % 3) * 24576;
        const char* bB = aB + 8192;
        if (kt < 15) asm volatile("s_waitcnt vmcnt(3)\ns_barrier" ::: "memory");
        else         asm volatile("s_waitcnt vmcnt(0)\ns_barrier" ::: "memory");
        if (kt < 14) STAGE((kt + 2) % 3, kt + 2);  // buf last read in kt-1
        {
            const int ph = (lhi ^ (llo >> 2)) << 4;
            bf16x8 aF[4], bF[4];
            #pragma unroll
            for (int mi = 0; mi < 4; ++mi)
                aF[mi] = *(const bf16x8*)(aB + (mr + mi * 16 + llo) * 64 + ph);
            #pragma unroll
            for (int ni = 0; ni < 4; ++ni)
                bF[ni] = *(const bf16x8*)(bB + (nc + ni * 16 + llo) * 64 + ph);
            __builtin_amdgcn_s_setprio(1);   // also a scheduling fence (r33 lesson)
            #pragma unroll
            for (int mi = 0; mi < 4; ++mi)
                #pragma unroll
                for (int ni = 0; ni < 4; ++ni)
                    acc[mi][ni] = __builtin_amdgcn_mfma_f32_16x16x32_bf16(
                        aF[mi], bF[ni], acc[mi][ni], 0, 0, 0);
            __builtin_amdgcn_s_setprio(0);
        }
    }
    __syncthreads();  // all reads done; safe to overlay eo on staging LDS

    unsigned short* eo = (unsigned short*)smem;
    #pragma unroll
    for (int ni = 0; ni < 4; ++ni) {
        const int col = nc + ni * 16 + llo;
        const float ebv = eb[n0 + col];
        #pragma unroll
        for (int mi = 0; mi < 4; ++mi) {
            #pragma unroll
            for (int j = 0; j < 4; ++j) {
                int row = mr + mi * 16 + lhi * 4 + j;
                eo[row * 264 + col] = f2bf(fmaxf(acc[mi][ni][j] + ebv, 0.f));
            }
        }
    }
    __syncthreads();
    // contraction: out[t,b,u] = sum_e eo[b,u,e] * gates[b][e*4+t] (float4/e)
    #pragma unroll
    for (int i = 0; i < 4; ++i) {
        int f = i * 512 + tid;
        int m = f >> 4, ul = f & 15;
        const unsigned short* er = eo + m * 264 + ul * 16;
        const float* gr = gates + (size_t)(b0 + m) * 64;
        float o0 = 0.f, o1 = 0.f, o2 = 0.f, o3 = 0.f;
        #pragma unroll
        for (int e = 0; e < 16; ++e) {
            const float v = bf2f(er[e]);
            const float4 gv = *(const float4*)(gr + e * 4);
            o0 = fmaf(v, gv.x, o0);
            o1 = fmaf(v, gv.y, o1);
            o2 = fmaf(v, gv.z, o2);
            o3 = fmaf(v, gv.w, o3);
        }
        size_t base = (size_t)(b0 + m) * Uu + (n0 >> 4) + ul;
        out[base] = o0;
        out[(size_t)Bsz * Uu + base] = o1;
        out[2 * (size_t)Bsz * Uu + base] = o2;
        out[3 * (size_t)Bsz * Uu + base] = o3;
    }
}

extern "C" void kernel_launch(void* const* d_in, const int* in_sizes, int n_in,
                              void* d_out, int out_size, void* d_ws, size_t ws_size,
                              hipStream_t stream) {
    const float* x  = (const float*)d_in[0];
    const float* ek = (const float*)d_in[1];
    const float* eb = (const float*)d_in[2];
    const float* gk = (const float*)d_in[3];
    const float* gb = (const float*)d_in[4];
    float* out = (float*)d_out;

    char* wsb = (char*)d_ws;
    float* gates       = (float*)wsb;                            // 4 MiB @ 0
    unsigned short* xb  = (unsigned short*)(wsb + (4u << 20));   // 16 MiB @ 4
    unsigned short* ekT = (unsigned short*)(wsb + (20u << 20));  // 2 MiB @ 20

    prep_kernel<<<512, 512, 0, stream>>>(x, gk, gb, ek, gates, xb, ekT);
    moe_kernel<<<(Bsz / BM) * (Nn / BN), 512, 0, stream>>>(xb, ekT, eb, gates, out);
}